// Round 6
// baseline (478.441 us; speedup 1.0000x reference)
//
#include <hip/hip_runtime.h>
#include <hip/hip_bf16.h>
#include <hip/hip_cooperative_groups.h>
#include <math.h>

namespace cg = cooperative_groups;

#define S_LEN  2048
#define DMODEL 512
#define NHEADS 8
#define DK     64
#define WIN    64

static constexpr float SCALE = 0.125f;

typedef short bf16x8 __attribute__((ext_vector_type(8)));
typedef float f32x4  __attribute__((ext_vector_type(4)));

__device__ __forceinline__ short bfh(float v)
{
    __hip_bfloat16 b = __float2bfloat16(v);
    return *reinterpret_cast<short*>(&b);
}
__device__ __forceinline__ float bf2f(short s)
{
    __hip_bfloat16 b = *reinterpret_cast<__hip_bfloat16*>(&s);
    return __bfloat162float(b);
}
__device__ __forceinline__ void split1(float v, short& h, short& l)
{
    h = bfh(v);
    l = bfh(v - bf2f(h));
}

// async global->LDS, 16B/lane; LDS dest = wave-uniform base + lane*16
__device__ __forceinline__ void dma16(const void* g, void* l)
{
    __builtin_amdgcn_global_load_lds(
        (const __attribute__((address_space(1))) unsigned int*)g,
        (__attribute__((address_space(3))) unsigned int*)l, 16, 0, 0);
}

// ---------------------------------------------------------------------------
// One cooperative kernel: cast -> QKV GEMM -> banded attention -> out GEMM.
// Grid 512 x 256 (2 blocks/CU, LDS-bound), grid.sync() between phases.
// ---------------------------------------------------------------------------
__global__ __launch_bounds__(256, 2)
void fused_lbsa(const float* __restrict__ x,
                const float* __restrict__ Wq, const float* __restrict__ bq,
                const float* __restrict__ Wk, const float* __restrict__ bk,
                const float* __restrict__ Wv, const float* __restrict__ bv,
                const float* __restrict__ Wo, const float* __restrict__ bo,
                float* __restrict__ out, char* __restrict__ ws)
{
    cg::grid_group grid = cg::this_grid();

    short* qh  = (short*)(ws);                // 2 MB each
    short* ql  = (short*)(ws + (2u << 20));
    short* kb  = (short*)(ws + (4u << 20));
    short* vbt = (short*)(ws + (6u << 20));   // V^T [512 dims][2048 pos]
    short* xh  = (short*)(ws + (8u << 20));
    short* xl  = (short*)(ws + (10u << 20));
    short* wqb = (short*)(ws + (12u << 20));  // 0.5 MB each
    short* wkb = (short*)(ws + (12u << 20) + 1 * (512u << 10));
    short* wvb = (short*)(ws + (12u << 20) + 2 * (512u << 10));
    short* wob = (short*)(ws + (12u << 20) + 3 * (512u << 10));
    short* abh = xh;    // xh/xl dead after phase B; attention output lands here
    short* abl = xl;

    __shared__ __align__(16) short U[32768];   // 64 KB union
    __shared__ float pmax[4][32];
    __shared__ float psum[4][32];

    const int bid  = blockIdx.x;
    const int tid  = threadIdx.x;
    const int lane = tid & 63;
    const int wv   = tid >> 6;
    const int col  = lane & 15;
    const int quad = lane >> 4;
    const int gid  = bid * 256 + tid;          // 0..131071

    // ================= Phase A: casts =================
    for (int i = gid; i < 262144; i += 131072) {
        const float4 v = ((const float4*)x)[i];
        short4 h4, l4;
        split1(v.x, h4.x, l4.x);
        split1(v.y, h4.y, l4.y);
        split1(v.z, h4.z, l4.z);
        split1(v.w, h4.w, l4.w);
        ((short4*)xh)[i] = h4;
        ((short4*)xl)[i] = l4;
    }
    for (int i = gid; i < 262144; i += 131072) {
        const int sel = i >> 16, off = i & 65535;
        const float* s; short* d;
        switch (sel) {
            case 0:  s = Wq; d = wqb; break;
            case 1:  s = Wk; d = wkb; break;
            case 2:  s = Wv; d = wvb; break;
            default: s = Wo; d = wob; break;
        }
        const float4 v = ((const float4*)s)[off];
        short4 o;
        o.x = bfh(v.x); o.y = bfh(v.y); o.z = bfh(v.z); o.w = bfh(v.w);
        ((short4*)d)[off] = o;
    }
    __threadfence();
    grid.sync();

    // ================= Phase B: QKV GEMM =================
    // 1536 tiles of 32 rows x 64 cols (z in {Q,K,V}); 3 per block; B slice
    // (64x512 bf16 = 64 KB) staged once per tile, XOR(row&7) chunk swizzle.
    for (int rep = 0; rep < 3; ++rep) {
        const int t    = bid + 512 * rep;
        const int z    = t >> 9;
        const int rem  = t & 511;
        const int col0 = (rem & 7) * 64;
        const int row0 = (rem >> 3) * 32;
        const short* Bg   = (z == 0) ? wqb : (z == 1) ? wkb : wvb;
        const float* bias = (z == 0) ? bq  : (z == 1) ? bk  : bv;

        __syncthreads();                       // previous tile's LDS reads done
        for (int i = wv; i < 64; i += 4) {     // issue = one row (64 chunks)
            const int j = lane ^ (i & 7);      // source chunk swizzle (low 3)
            dma16(Bg + (size_t)(col0 + i) * 512 + j * 8, U + i * 512);
        }
        __syncthreads();                       // vmcnt(0) drain

        f32x4 acc[2];
        acc[0] = (f32x4)0.0f;
        acc[1] = (f32x4)0.0f;
        const int m  = row0 + (wv >> 1) * 16 + col;
        const int nb = (wv & 1) * 32;
#pragma unroll 4
        for (int kc = 0; kc < 16; ++kc) {
            const bf16x8 ah = *(const bf16x8*)(xh + (size_t)m * 512 + kc * 32 + quad * 8);
            const bf16x8 al = *(const bf16x8*)(xl + (size_t)m * 512 + kc * 32 + quad * 8);
#pragma unroll
            for (int nj = 0; nj < 2; ++nj) {
                const int n = nb + nj * 16 + col;
                const bf16x8 bf = *(const bf16x8*)&U[n * 512 + ((kc * 4 + quad) ^ (n & 7)) * 8];
                acc[nj] = __builtin_amdgcn_mfma_f32_16x16x32_bf16(ah, bf, acc[nj], 0, 0, 0);
                acc[nj] = __builtin_amdgcn_mfma_f32_16x16x32_bf16(al, bf, acc[nj], 0, 0, 0);
            }
        }
#pragma unroll
        for (int nj = 0; nj < 2; ++nj) {
            const int cc = col0 + nb + nj * 16 + col;
            const float bias_v = bias[cc];
#pragma unroll
            for (int e = 0; e < 4; ++e) {
                const int row = row0 + (wv >> 1) * 16 + quad * 4 + e;
                const float val = acc[nj][e] + bias_v;
                if (z == 0) {
                    short hh, ll;
                    split1(val, hh, ll);
                    qh[(size_t)row * 512 + cc] = hh;
                    ql[(size_t)row * 512 + cc] = ll;
                } else if (z == 1) {
                    kb[(size_t)row * 512 + cc] = bfh(val);
                } else {
                    vbt[(size_t)cc * 2048 + row] = bfh(val);   // transposed
                }
            }
        }
    }
    __threadfence();
    grid.sync();

    // ================= Phase C: banded attention =================
    {
        short* VtS = U;                  // [64 dims][32 chunks] (24 live)
        short* KS  = U + 16384;          // [192 pos][64 shorts]; aliased by P
        short* QhS = U + 28672;          // [32][64]
        short* QlS = U + 30720;          // [32][64]
        short* PS  = KS;                 // P [32][200] after QK phase

        const int h  = bid & 7;
        const int t0 = (bid >> 3) * 32;

        // ---- DMA staging: Qh(4), Ql(4), K(24) — 8-row groups ----
        {
            const int lr = lane >> 3;
            const int lc = lane & 7;
            for (int i = wv; i < 32; i += 4) {
                const short* src; short* dst; int r;
                if (i < 4) {
                    r = i * 8 + lr;
                    src = qh + (size_t)(t0 + r) * 512 + h * 64;
                    dst = QhS + i * 512;
                } else if (i < 8) {
                    const int g = i - 4;
                    r = g * 8 + lr;
                    src = ql + (size_t)(t0 + r) * 512 + h * 64;
                    dst = QlS + g * 512;
                } else {
                    const int g = i - 8;
                    r = g * 8 + lr;
                    int pos = t0 - 64 + r;
                    pos = pos < 0 ? 0 : (pos > 2047 ? 2047 : pos);  // masked later
                    src = kb + (size_t)pos * 512 + h * 64;
                    dst = KS + g * 512;
                }
                const int cs = lc ^ (r & 7);
                dma16(src + cs * 8, dst);
            }
            // V^T window: 64 dims x 24 chunks (192 pos), rows padded to 32
            for (int i = wv; i < 32; i += 4) {
                const int q = i * 64 + lane;
                const int d = q >> 5;
                const int b = q & 31;
                const int j0 = (b < 24) ? b : 0;
                const int j = j0 ^ (d & 7);
                int p0 = t0 - 64 + j * 8;
                p0 = p0 < 0 ? 0 : (p0 > 2040 ? 2040 : p0);
                dma16(vbt + (size_t)(h * 64 + d) * 2048 + p0, VtS + i * 512);
            }
        }
        __syncthreads();

        // ---- QK^T: wave covers positions [wv*48, wv*48+48) ----
        f32x4 sacc[2][3];
#pragma unroll
        for (int mi = 0; mi < 2; ++mi)
#pragma unroll
            for (int nj = 0; nj < 3; ++nj)
                sacc[mi][nj] = (f32x4)0.0f;

#pragma unroll
        for (int ks = 0; ks < 2; ++ks) {
            const int q0 = ks * 4 + quad;
            bf16x8 aqh[2], aql[2];
#pragma unroll
            for (int mi = 0; mi < 2; ++mi) {
                const int mm = mi * 16 + col;
                const int p = q0 ^ (mm & 7);
                aqh[mi] = *(const bf16x8*)&QhS[mm * 64 + p * 8];
                aql[mi] = *(const bf16x8*)&QlS[mm * 64 + p * 8];
            }
#pragma unroll
            for (int nj = 0; nj < 3; ++nj) {
                const int n = wv * 48 + nj * 16 + col;
                const int p = q0 ^ (n & 7);
                const bf16x8 bkf = *(const bf16x8*)&KS[n * 64 + p * 8];
#pragma unroll
                for (int mi = 0; mi < 2; ++mi) {
                    sacc[mi][nj] = __builtin_amdgcn_mfma_f32_16x16x32_bf16(aqh[mi], bkf, sacc[mi][nj], 0, 0, 0);
                    sacc[mi][nj] = __builtin_amdgcn_mfma_f32_16x16x32_bf16(aql[mi], bkf, sacc[mi][nj], 0, 0, 0);
                }
            }
        }

        // ---- mask + scale ----
        float pv[2][3][4];
#pragma unroll
        for (int mi = 0; mi < 2; ++mi)
#pragma unroll
            for (int nj = 0; nj < 3; ++nj)
#pragma unroll
                for (int e = 0; e < 4; ++e) {
                    const int r32 = mi * 16 + quad * 4 + e;
                    const int n   = wv * 48 + nj * 16 + col;
                    const int pos = t0 - 64 + n;
                    const int d   = n - r32;
                    const bool valid = (pos >= 0) && (pos < S_LEN) && (d >= 0) && (d <= 128);
                    pv[mi][nj][e] = valid ? sacc[mi][nj][e] * SCALE : -__builtin_inff();
                }

        // ---- wave-partial row max ----
#pragma unroll
        for (int mi = 0; mi < 2; ++mi)
#pragma unroll
            for (int e = 0; e < 4; ++e) {
                float mx = fmaxf(fmaxf(pv[mi][0][e], pv[mi][1][e]), pv[mi][2][e]);
#pragma unroll
                for (int off = 1; off < 16; off <<= 1)
                    mx = fmaxf(mx, __shfl_xor(mx, off));
                if ((lane & 15) == 0) pmax[wv][mi * 16 + quad * 4 + e] = mx;
            }
        __syncthreads();   // pmax done; K/Q reads done -> P may overwrite KS

        // ---- exp + wave-partial sums + write P (bf16) ----
#pragma unroll
        for (int mi = 0; mi < 2; ++mi)
#pragma unroll
            for (int e = 0; e < 4; ++e) {
                const int r32 = mi * 16 + quad * 4 + e;
                const float m = fmaxf(fmaxf(pmax[0][r32], pmax[1][r32]),
                                      fmaxf(pmax[2][r32], pmax[3][r32]));
                float ss = 0.f;
#pragma unroll
                for (int nj = 0; nj < 3; ++nj) {
                    const float p = __expf(pv[mi][nj][e] - m);
                    pv[mi][nj][e] = p;
                    ss += p;
                }
#pragma unroll
                for (int off = 1; off < 16; off <<= 1)
                    ss += __shfl_xor(ss, off);
                if ((lane & 15) == 0) psum[wv][r32] = ss;
#pragma unroll
                for (int nj = 0; nj < 3; ++nj) {
                    const int n = wv * 48 + nj * 16 + col;
                    PS[r32 * 200 + n] = bfh(pv[mi][nj][e]);
                }
            }
        __syncthreads();

        // ---- PV ----
        const int mi = wv >> 1;
        f32x4 oacc[2];
        oacc[0] = (f32x4)0.0f;
        oacc[1] = (f32x4)0.0f;
#pragma unroll
        for (int ks = 0; ks < 6; ++ks) {
            const bf16x8 pa = *(const bf16x8*)&PS[(mi * 16 + col) * 200 + ks * 32 + quad * 8];
#pragma unroll
            for (int t = 0; t < 2; ++t) {
                const int d = ((wv & 1) * 2 + t) * 16 + col;
                const int j = (ks * 4 + quad) ^ (d & 7);
                const bf16x8 vf = *(const bf16x8*)&VtS[d * 256 + j * 8];
                oacc[t] = __builtin_amdgcn_mfma_f32_16x16x32_bf16(pa, vf, oacc[t], 0, 0, 0);
            }
        }

        // ---- epilogue: normalize, split hi/lo for out-GEMM ----
        float linv[4];
#pragma unroll
        for (int e = 0; e < 4; ++e) {
            const int r32 = mi * 16 + quad * 4 + e;
            linv[e] = 1.0f / (psum[0][r32] + psum[1][r32] + psum[2][r32] + psum[3][r32]);
        }
#pragma unroll
        for (int t = 0; t < 2; ++t) {
            const int nj = (wv & 1) * 2 + t;
#pragma unroll
            for (int e = 0; e < 4; ++e) {
                const int r32 = mi * 16 + quad * 4 + e;
                const float val = oacc[t][e] * linv[e];
                short hh, ll;
                split1(val, hh, ll);
                const size_t idx = (size_t)(t0 + r32) * 512 + h * 64 + nj * 16 + col;
                abh[idx] = hh;
                abl[idx] = ll;
            }
        }
    }
    __threadfence();
    grid.sync();

    // ================= Phase D: output projection =================
    {
        const int col0 = (bid & 7) * 64;
        const int row0 = (bid >> 3) * 32;

        for (int i = wv; i < 64; i += 4) {
            const int j = lane ^ (i & 7);
            dma16(wob + (size_t)(col0 + i) * 512 + j * 8, U + i * 512);
        }
        __syncthreads();

        f32x4 acc[2];
        acc[0] = (f32x4)0.0f;
        acc[1] = (f32x4)0.0f;
        const int m  = row0 + (wv >> 1) * 16 + col;
        const int nb = (wv & 1) * 32;
#pragma unroll 4
        for (int kc = 0; kc < 16; ++kc) {
            const bf16x8 ah = *(const bf16x8*)(abh + (size_t)m * 512 + kc * 32 + quad * 8);
            const bf16x8 al = *(const bf16x8*)(abl + (size_t)m * 512 + kc * 32 + quad * 8);
#pragma unroll
            for (int nj = 0; nj < 2; ++nj) {
                const int n = nb + nj * 16 + col;
                const bf16x8 bf = *(const bf16x8*)&U[n * 512 + ((kc * 4 + quad) ^ (n & 7)) * 8];
                acc[nj] = __builtin_amdgcn_mfma_f32_16x16x32_bf16(ah, bf, acc[nj], 0, 0, 0);
                acc[nj] = __builtin_amdgcn_mfma_f32_16x16x32_bf16(al, bf, acc[nj], 0, 0, 0);
            }
        }
#pragma unroll
        for (int nj = 0; nj < 2; ++nj) {
            const int cc = col0 + nb + nj * 16 + col;
            const float bias_v = bo[cc];
#pragma unroll
            for (int e = 0; e < 4; ++e) {
                const int row = row0 + (wv >> 1) * 16 + quad * 4 + e;
                out[(size_t)row * 512 + cc] = acc[nj][e] + bias_v;
            }
        }
    }
}

// ---------------------------------------------------------------------------
extern "C" void kernel_launch(void* const* d_in, const int* in_sizes, int n_in,
                              void* d_out, int out_size, void* d_ws, size_t ws_size,
                              hipStream_t stream)
{
    const float* x  = (const float*)d_in[0];
    const float* Wq = (const float*)d_in[1];
    const float* bq = (const float*)d_in[2];
    const float* Wk = (const float*)d_in[3];
    const float* bk = (const float*)d_in[4];
    const float* Wv = (const float*)d_in[5];
    const float* bv = (const float*)d_in[6];
    const float* Wo = (const float*)d_in[7];
    const float* bo = (const float*)d_in[8];
    float* outp = (float*)d_out;
    char* wsp = (char*)d_ws;

    void* kargs[] = {
        (void*)&x,
        (void*)&Wq, (void*)&bq,
        (void*)&Wk, (void*)&bk,
        (void*)&Wv, (void*)&bv,
        (void*)&Wo, (void*)&bo,
        (void*)&outp, (void*)&wsp,
    };
    hipLaunchCooperativeKernel((const void*)fused_lbsa, dim3(512), dim3(256),
                               kargs, 0, stream);
}

// Round 7
// 112.480 us; speedup vs baseline: 4.2536x; 4.2536x over previous
//
#include <hip/hip_runtime.h>
#include <hip/hip_bf16.h>
#include <math.h>

#define S_LEN  2048
#define DMODEL 512
#define NHEADS 8
#define DK     64
#define WIN    64

static constexpr float SCALE = 0.125f;

typedef short bf16x8 __attribute__((ext_vector_type(8)));
typedef float f32x4  __attribute__((ext_vector_type(4)));

// ---------------------------------------------------------------------------
// helpers
// ---------------------------------------------------------------------------
__device__ __forceinline__ short bfh(float v)
{
    __hip_bfloat16 b = __float2bfloat16(v);
    return *reinterpret_cast<short*>(&b);
}
__device__ __forceinline__ float bf2f(short s)
{
    __hip_bfloat16 b = *reinterpret_cast<__hip_bfloat16*>(&s);
    return __bfloat162float(b);
}
__device__ __forceinline__ void split1(float v, short& h, short& l)
{
    h = bfh(v);
    l = bfh(v - bf2f(h));
}
// 8 consecutive fp32 -> bf16 hi/lo fragments
__device__ __forceinline__ void split8(const float4 a0, const float4 a1,
                                       bf16x8& h8, bf16x8& l8)
{
    short hh, ll;
    split1(a0.x, hh, ll); h8[0] = hh; l8[0] = ll;
    split1(a0.y, hh, ll); h8[1] = hh; l8[1] = ll;
    split1(a0.z, hh, ll); h8[2] = hh; l8[2] = ll;
    split1(a0.w, hh, ll); h8[3] = hh; l8[3] = ll;
    split1(a1.x, hh, ll); h8[4] = hh; l8[4] = ll;
    split1(a1.y, hh, ll); h8[5] = hh; l8[5] = ll;
    split1(a1.z, hh, ll); h8[6] = hh; l8[6] = ll;
    split1(a1.w, hh, ll); h8[7] = hh; l8[7] = ll;
}

// async global->LDS, 16B per lane; lds dest = wave-uniform base + lane*16
__device__ __forceinline__ void dma16(const void* g, void* l)
{
    __builtin_amdgcn_global_load_lds(
        (const __attribute__((address_space(1))) unsigned int*)g,
        (__attribute__((address_space(3))) unsigned int*)l, 16, 0, 0);
}

// ---------------------------------------------------------------------------
// weight cast: z=0..3 -> Wq,Wk,Wv,Wo fp32 -> bf16
// ---------------------------------------------------------------------------
__global__ __launch_bounds__(256)
void cast_w(const float* __restrict__ wq, const float* __restrict__ wk,
            const float* __restrict__ wv, const float* __restrict__ wo,
            short* __restrict__ wqb, short* __restrict__ wkb,
            short* __restrict__ wvb, short* __restrict__ wob)
{
    const float* s; short* d;
    switch (blockIdx.z) {
        case 0:  s = wq; d = wqb; break;
        case 1:  s = wk; d = wkb; break;
        case 2:  s = wv; d = wvb; break;
        default: s = wo; d = wob; break;
    }
    for (int i = blockIdx.x * 256 + threadIdx.x; i < 65536; i += gridDim.x * 256) {
        const float4 v = ((const float4*)s)[i];
        short4 o;
        o.x = bfh(v.x); o.y = bfh(v.y); o.z = bfh(v.z); o.w = bfh(v.w);
        ((short4*)d)[i] = o;
    }
}

// ---------------------------------------------------------------------------
// QKV GEMM, streaming / barrier-light:
//  - B tile (64 cols x 512 k bf16) staged in TWO one-shot LDS phases,
//    chunk XOR-swizzled -> fragment ds_read_b128 at 2-way alias (free).
//  - A read as fp32 straight from x, split hi/lo in-register (VALU hides
//    under the MFMA pipe; bytes/lane identical to pre-split bf16 hi+lo).
// 128 threads = 2 waves; wave covers 32 rows.
// z=0 -> Q (bf16 hi/lo), z=1 -> K (bf16), z=2 -> V^T (bf16, [dim][pos]).
// ---------------------------------------------------------------------------
__global__ __launch_bounds__(128)
void gemm_qkv4(const float* __restrict__ x,
               const short* __restrict__ wqb, const short* __restrict__ wkb,
               const short* __restrict__ wvb,
               const float* __restrict__ bq, const float* __restrict__ bk,
               const float* __restrict__ bv,
               short* __restrict__ qh, short* __restrict__ ql,
               short* __restrict__ kb, short* __restrict__ vbt)
{
    __shared__ __align__(16) short sB[64 * 256];   // 64 cols x 256 k (one phase)

    const int z = blockIdx.z;
    const short* Bg   = (z == 0) ? wqb : (z == 1) ? wkb : wvb;
    const float* bias = (z == 0) ? bq  : (z == 1) ? bk  : bv;
    const int row0 = blockIdx.y * 64;
    const int col0 = blockIdx.x * 64;
    const int tid  = threadIdx.x;
    const int lane = tid & 63;
    const int wv   = tid >> 6;
    const int col  = lane & 15;
    const int quad = lane >> 4;

    f32x4 acc[2][4];
#pragma unroll
    for (int mi = 0; mi < 2; ++mi)
#pragma unroll
        for (int nj = 0; nj < 4; ++nj)
            acc[mi][nj] = (f32x4)0.0f;

    for (int ph = 0; ph < 2; ++ph) {
        __syncthreads();   // previous phase's LDS reads complete
        for (int i = wv; i < 32; i += 2) {
            const int q = i * 64 + lane;     // dest 16B chunk index
            const int r = q >> 5;            // B row (0..63)
            const int b = q & 31;            // chunk within row
            const int j = b ^ (r & 7);       // source chunk (swizzle low 3)
            dma16(Bg + (size_t)(col0 + r) * 512 + ph * 256 + j * 8, sB + i * 512);
        }
        __syncthreads();   // vmcnt(0) drain

#pragma unroll
        for (int kc = 0; kc < 8; ++kc) {
            const int k = ph * 256 + kc * 32;
            bf16x8 ah[2], al[2];
#pragma unroll
            for (int mi = 0; mi < 2; ++mi) {
                const int m = row0 + wv * 32 + mi * 16 + col;
                const float* xp = x + (size_t)m * 512 + k + quad * 8;
                const float4 a0 = *(const float4*)xp;
                const float4 a1 = *(const float4*)(xp + 4);
                split8(a0, a1, ah[mi], al[mi]);
            }
#pragma unroll
            for (int nj = 0; nj < 4; ++nj) {
                const int n = nj * 16 + col;
                const int j = (kc * 4 + quad) ^ (n & 7);
                const bf16x8 bf = *(const bf16x8*)&sB[n * 256 + j * 8];
#pragma unroll
                for (int mi = 0; mi < 2; ++mi) {
                    acc[mi][nj] = __builtin_amdgcn_mfma_f32_16x16x32_bf16(ah[mi], bf, acc[mi][nj], 0, 0, 0);
                    acc[mi][nj] = __builtin_amdgcn_mfma_f32_16x16x32_bf16(al[mi], bf, acc[mi][nj], 0, 0, 0);
                }
            }
        }
    }

    // epilogue
#pragma unroll
    for (int nj = 0; nj < 4; ++nj) {
        const int cc = col0 + nj * 16 + col;
        const float bias_v = bias[cc];
#pragma unroll
        for (int mi = 0; mi < 2; ++mi) {
#pragma unroll
            for (int e = 0; e < 4; ++e) {
                const int row = row0 + wv * 32 + mi * 16 + quad * 4 + e;
                const float val = acc[mi][nj][e] + bias_v;
                if (z == 0) {
                    short hh, ll;
                    split1(val, hh, ll);
                    qh[(size_t)row * 512 + cc] = hh;
                    ql[(size_t)row * 512 + cc] = ll;
                } else if (z == 1) {
                    kb[(size_t)row * 512 + cc] = bfh(val);
                } else {
                    vbt[(size_t)cc * 2048 + row] = bfh(val);   // transposed
                }
            }
        }
    }
}

// ---------------------------------------------------------------------------
// Output projection GEMM: A = attention output (single bf16), fp32 out.
// ---------------------------------------------------------------------------
__global__ __launch_bounds__(128)
void gemm_out4(const short* __restrict__ ah_g,
               const short* __restrict__ wob, const float* __restrict__ bo,
               float* __restrict__ out)
{
    __shared__ __align__(16) short sB[64 * 256];

    const int row0 = blockIdx.y * 32;
    const int col0 = blockIdx.x * 64;
    const int tid  = threadIdx.x;
    const int lane = tid & 63;
    const int wv   = tid >> 6;
    const int col  = lane & 15;
    const int quad = lane >> 4;

    f32x4 acc[4];
#pragma unroll
    for (int nj = 0; nj < 4; ++nj)
        acc[nj] = (f32x4)0.0f;

    for (int ph = 0; ph < 2; ++ph) {
        __syncthreads();
        for (int i = wv; i < 32; i += 2) {
            const int q = i * 64 + lane;
            const int r = q >> 5;
            const int b = q & 31;
            const int j = b ^ (r & 7);
            dma16(wob + (size_t)(col0 + r) * 512 + ph * 256 + j * 8, sB + i * 512);
        }
        __syncthreads();

#pragma unroll
        for (int kc = 0; kc < 8; ++kc) {
            const int k = ph * 256 + kc * 32;
            const int m = row0 + wv * 16 + col;
            const bf16x8 ah = *(const bf16x8*)(ah_g + (size_t)m * 512 + k + quad * 8);
#pragma unroll
            for (int nj = 0; nj < 4; ++nj) {
                const int n = nj * 16 + col;
                const int j = (kc * 4 + quad) ^ (n & 7);
                const bf16x8 bf = *(const bf16x8*)&sB[n * 256 + j * 8];
                acc[nj] = __builtin_amdgcn_mfma_f32_16x16x32_bf16(ah, bf, acc[nj], 0, 0, 0);
            }
        }
    }

#pragma unroll
    for (int nj = 0; nj < 4; ++nj) {
        const int cc = col0 + nj * 16 + col;
        const float bias_v = bo[cc];
#pragma unroll
        for (int e = 0; e < 4; ++e) {
            const int row = row0 + wv * 16 + quad * 4 + e;
            out[(size_t)row * 512 + cc] = acc[nj][e] + bias_v;
        }
    }
}

// ---------------------------------------------------------------------------
// MFMA banded attention (round-5 body; epilogue writes single bf16).
// ---------------------------------------------------------------------------
__global__ __launch_bounds__(256)
void banded_attn4(const short* __restrict__ qh, const short* __restrict__ ql,
                  const short* __restrict__ kb, const short* __restrict__ vbt,
                  short* __restrict__ abh)
{
    __shared__ __align__(16) short VtS[64 * 256];   // V^T [dim][32 chunks]
    __shared__ __align__(16) short KS [192 * 64];   // K window; aliased by P
    __shared__ __align__(16) short QhS[32 * 64];
    __shared__ __align__(16) short QlS[32 * 64];
    __shared__ float pmax[4][32];
    __shared__ float psum[4][32];
    short* PS = KS;                                 // P [32][200], after QK

    const int h    = blockIdx.x;
    const int t0   = blockIdx.y * 32;
    const int tid  = threadIdx.x;
    const int lane = tid & 63;
    const int wv   = tid >> 6;
    const int col  = lane & 15;
    const int quad = lane >> 4;

    // ---- DMA staging: Qh (4 issues), Ql (4), K (24) — 8-row groups ----
    {
        const int lr = lane >> 3;
        const int lc = lane & 7;
        for (int i = wv; i < 32; i += 4) {
            const short* src; short* dst; int r;
            if (i < 4) {
                r = i * 8 + lr;
                src = qh + (size_t)(t0 + r) * 512 + h * 64;
                dst = QhS + i * 512;
            } else if (i < 8) {
                const int g = i - 4;
                r = g * 8 + lr;
                src = ql + (size_t)(t0 + r) * 512 + h * 64;
                dst = QlS + g * 512;
            } else {
                const int g = i - 8;
                r = g * 8 + lr;
                int pos = t0 - 64 + r;
                pos = pos < 0 ? 0 : (pos > 2047 ? 2047 : pos);   // masked later
                src = kb + (size_t)pos * 512 + h * 64;
                dst = KS + g * 512;
            }
            const int cs = lc ^ (r & 7);
            dma16(src + cs * 8, dst);
        }
        // ---- V^T window: 64 dims x 24 chunks (192 pos), rows padded to 32 ----
        for (int i = wv; i < 32; i += 4) {
            const int q = i * 64 + lane;
            const int d = q >> 5;            // dim 0..63
            const int b = q & 31;            // dest chunk in row
            const int j0 = (b < 24) ? b : 0; // dead chunks load dummy
            const int j = j0 ^ (d & 7);
            int p0 = t0 - 64 + j * 8;
            p0 = p0 < 0 ? 0 : (p0 > 2040 ? 2040 : p0);
            dma16(vbt + (size_t)(h * 64 + d) * 2048 + p0, VtS + i * 512);
        }
    }
    __syncthreads();

    // ---- QK^T: wave covers positions [wv*48, wv*48+48) ----
    f32x4 sacc[2][3];
#pragma unroll
    for (int mi = 0; mi < 2; ++mi)
#pragma unroll
        for (int nj = 0; nj < 3; ++nj)
            sacc[mi][nj] = (f32x4)0.0f;

#pragma unroll
    for (int ks = 0; ks < 2; ++ks) {
        const int q0 = ks * 4 + quad;
        bf16x8 aqh[2], aql[2];
#pragma unroll
        for (int mi = 0; mi < 2; ++mi) {
            const int m = mi * 16 + col;
            const int p = q0 ^ (m & 7);
            aqh[mi] = *(const bf16x8*)&QhS[m * 64 + p * 8];
            aql[mi] = *(const bf16x8*)&QlS[m * 64 + p * 8];
        }
#pragma unroll
        for (int nj = 0; nj < 3; ++nj) {
            const int n = wv * 48 + nj * 16 + col;
            const int p = q0 ^ (n & 7);
            const bf16x8 bkf = *(const bf16x8*)&KS[n * 64 + p * 8];
#pragma unroll
            for (int mi = 0; mi < 2; ++mi) {
                sacc[mi][nj] = __builtin_amdgcn_mfma_f32_16x16x32_bf16(aqh[mi], bkf, sacc[mi][nj], 0, 0, 0);
                sacc[mi][nj] = __builtin_amdgcn_mfma_f32_16x16x32_bf16(aql[mi], bkf, sacc[mi][nj], 0, 0, 0);
            }
        }
    }

    // ---- mask + scale ----
    float pv[2][3][4];
#pragma unroll
    for (int mi = 0; mi < 2; ++mi)
#pragma unroll
        for (int nj = 0; nj < 3; ++nj)
#pragma unroll
            for (int e = 0; e < 4; ++e) {
                const int r32 = mi * 16 + quad * 4 + e;
                const int n   = wv * 48 + nj * 16 + col;
                const int pos = t0 - 64 + n;
                const int d   = n - r32;
                const bool valid = (pos >= 0) && (pos < S_LEN) && (d >= 0) && (d <= 128);
                pv[mi][nj][e] = valid ? sacc[mi][nj][e] * SCALE : -__builtin_inff();
            }

    // ---- wave-partial row max ----
#pragma unroll
    for (int mi = 0; mi < 2; ++mi)
#pragma unroll
        for (int e = 0; e < 4; ++e) {
            float mx = fmaxf(fmaxf(pv[mi][0][e], pv[mi][1][e]), pv[mi][2][e]);
#pragma unroll
            for (int off = 1; off < 16; off <<= 1)
                mx = fmaxf(mx, __shfl_xor(mx, off));
            if ((lane & 15) == 0) pmax[wv][mi * 16 + quad * 4 + e] = mx;
        }
    __syncthreads();   // pmax done; K/Q reads done -> P may overwrite KS

    // ---- exp + wave-partial sums + write P (single bf16) ----
#pragma unroll
    for (int mi = 0; mi < 2; ++mi)
#pragma unroll
        for (int e = 0; e < 4; ++e) {
            const int r32 = mi * 16 + quad * 4 + e;
            const float m = fmaxf(fmaxf(pmax[0][r32], pmax[1][r32]),
                                  fmaxf(pmax[2][r32], pmax[3][r32]));
            float ss = 0.f;
#pragma unroll
            for (int nj = 0; nj < 3; ++nj) {
                const float p = __expf(pv[mi][nj][e] - m);
                pv[mi][nj][e] = p;
                ss += p;
            }
#pragma unroll
            for (int off = 1; off < 16; off <<= 1)
                ss += __shfl_xor(ss, off);
            if ((lane & 15) == 0) psum[wv][r32] = ss;
#pragma unroll
            for (int nj = 0; nj < 3; ++nj) {
                const int n = wv * 48 + nj * 16 + col;
                PS[r32 * 200 + n] = bfh(pv[mi][nj][e]);
            }
        }
    __syncthreads();

    // ---- PV ----
    const int mi = wv >> 1;
    f32x4 oacc[2];
    oacc[0] = (f32x4)0.0f;
    oacc[1] = (f32x4)0.0f;
#pragma unroll
    for (int ks = 0; ks < 6; ++ks) {
        const bf16x8 pa = *(const bf16x8*)&PS[(mi * 16 + col) * 200 + ks * 32 + quad * 8];
#pragma unroll
        for (int t = 0; t < 2; ++t) {
            const int d = ((wv & 1) * 2 + t) * 16 + col;
            const int j = (ks * 4 + quad) ^ (d & 7);
            const bf16x8 vf = *(const bf16x8*)&VtS[d * 256 + j * 8];
            oacc[t] = __builtin_amdgcn_mfma_f32_16x16x32_bf16(pa, vf, oacc[t], 0, 0, 0);
        }
    }

    // ---- epilogue: normalize, write single bf16 for out-GEMM ----
    float linv[4];
#pragma unroll
    for (int e = 0; e < 4; ++e) {
        const int r32 = mi * 16 + quad * 4 + e;
        linv[e] = 1.0f / (psum[0][r32] + psum[1][r32] + psum[2][r32] + psum[3][r32]);
    }
#pragma unroll
    for (int t = 0; t < 2; ++t) {
        const int nj = (wv & 1) * 2 + t;
#pragma unroll
        for (int e = 0; e < 4; ++e) {
            const int r32 = mi * 16 + quad * 4 + e;
            const float val = oacc[t][e] * linv[e];
            const size_t idx = (size_t)(t0 + r32) * 512 + h * 64 + nj * 16 + col;
            abh[idx] = bfh(val);
        }
    }
}

// ---------------------------------------------------------------------------
extern "C" void kernel_launch(void* const* d_in, const int* in_sizes, int n_in,
                              void* d_out, int out_size, void* d_ws, size_t ws_size,
                              hipStream_t stream)
{
    const float* x  = (const float*)d_in[0];
    const float* Wq = (const float*)d_in[1];
    const float* bq = (const float*)d_in[2];
    const float* Wk = (const float*)d_in[3];
    const float* bk = (const float*)d_in[4];
    const float* Wv = (const float*)d_in[5];
    const float* bv = (const float*)d_in[6];
    const float* Wo = (const float*)d_in[7];
    const float* bo = (const float*)d_in[8];
    float* out = (float*)d_out;

    char* ws = (char*)d_ws;
    short* qh  = (short*)(ws);                          // 2 MB
    short* ql  = (short*)(ws + (2u << 20));             // 2 MB
    short* kb  = (short*)(ws + (4u << 20));             // 2 MB
    short* vbt = (short*)(ws + (6u << 20));             // 2 MB (transposed V)
    short* abh = (short*)(ws + (8u << 20));             // 2 MB (attn out bf16)
    short* wqb = (short*)(ws + (12u << 20));            // 0.5 MB each
    short* wkb = (short*)(ws + (12u << 20) + 1 * (512u << 10));
    short* wvb = (short*)(ws + (12u << 20) + 2 * (512u << 10));
    short* wob = (short*)(ws + (12u << 20) + 3 * (512u << 10));

    dim3 gw(64, 1, 4);
    cast_w<<<gw, 256, 0, stream>>>(Wq, Wk, Wv, Wo, wqb, wkb, wvb, wob);

    dim3 gq(DMODEL / 64, S_LEN / 64, 3);                // 8 x 32 x 3 = 768 blocks
    gemm_qkv4<<<gq, 128, 0, stream>>>(x, wqb, wkb, wvb,
                                      bq, bk, bv, qh, ql, kb, vbt);

    dim3 ga(NHEADS, S_LEN / 32);                        // 512 blocks
    banded_attn4<<<ga, 256, 0, stream>>>(qh, ql, kb, vbt, abh);

    dim3 go(DMODEL / 64, S_LEN / 32);                   // 8 x 64 = 512 blocks
    gemm_out4<<<go, 128, 0, stream>>>(abh, wob, bo, out);
}